// Round 12
// baseline (30.126 us; speedup 1.0000x reference)
//
#include <hip/hip_runtime.h>

#define B 16
#define T 2048
#define D 1024
#define NSLICE 32            // slice-blocks per batch
#define SLICE (D / NSLICE)   // 32 floats = 8 float4 per block

typedef float f32x4 __attribute__((ext_vector_type(4)));

// Kernel 1: EXACT R6 structure (best known: 18.24us) — single kernel,
// slice-columns, single-writer stores, plain (cacheable) loads.
__global__ __launch_bounds__(256, 4) void fused1_kernel(
    const float* __restrict__ input,
    const int* __restrict__ lengths,
    const float* __restrict__ weights,
    float* __restrict__ out) {
    const int b   = blockIdx.x >> 5;
    const int s   = blockIdx.x & 31;
    const int tid = threadIdx.x;
    const int c   = tid & 7;
    const int rp  = tid >> 3;
    const int len = lengths[b];

    const float4* __restrict__ in4 =
        (const float4*)input + (size_t)b * T * (D / 4) + s * (SLICE / 4) + c;

    float4 acc = make_float4(0.f, 0.f, 0.f, 0.f);

    const int nfull = len >> 5;
    const float*  wr = weights + rp;
    const float4* p  = in4 + (size_t)rp * (D / 4);
#pragma unroll 4
    for (int it = 0; it < nfull; ++it) {
        const float  cw = expf(wr[it * 32]);
        const float4 v  = p[(size_t)it * 32 * (D / 4)];
        acc.x = fmaf(cw, v.x, acc.x);
        acc.y = fmaf(cw, v.y, acc.y);
        acc.z = fmaf(cw, v.z, acc.z);
        acc.w = fmaf(cw, v.w, acc.w);
    }
    const int r = (nfull << 5) + rp;
    if (r < len) {
        const float  cw = expf(weights[r]);
        const float4 v  = in4[(size_t)r * (D / 4)];
        acc.x = fmaf(cw, v.x, acc.x);
        acc.y = fmaf(cw, v.y, acc.y);
        acc.z = fmaf(cw, v.z, acc.z);
        acc.w = fmaf(cw, v.w, acc.w);
    }

    float lsum = 0.f;
#pragma unroll
    for (int i = 0; i < 8; ++i)
        lsum += expf(weights[tid * 8 + i]);
#pragma unroll
    for (int off = 32; off > 0; off >>= 1)
        lsum += __shfl_xor(lsum, off);
    __shared__ float red[4];
    if ((tid & 63) == 0) red[tid >> 6] = lsum;
    __syncthreads();
    const float inv = 1.f / (red[0] + red[1] + red[2] + red[3]);

    __shared__ float4 lds[32][8];
    lds[rp][c] = acc;
    __syncthreads();
#pragma unroll
    for (int off = 16; off > 0; off >>= 1) {
        if (rp < off) {
            const float4 o = lds[rp + off][c];
            acc.x += o.x; acc.y += o.y; acc.z += o.z; acc.w += o.w;
            lds[rp][c] = acc;
        }
        __syncthreads();
    }

    if (tid < 8) {
        const float4 r4 = make_float4(acc.x * inv, acc.y * inv,
                                      acc.z * inv, acc.w * inv);
        ((float4*)out)[b * (D / 4) + s * (SLICE / 4) + tid] = r4;
    }
}

// Kernel 2: PURE-READ PROBE. Identical grid/access pattern to kernel 1,
// but only sums the rows (no expf, no tree, no epilogue) and plain-stores
// each thread's accumulator to ws (2MB). Marginal dur vs R6's 18.24us
// = L3-hot raw stream time + one node cost. Decides M2 (stream BW-bound,
// ~4.5 TB/s pattern floor -> ROOFLINE) vs M3 (fixed overhead dominates).
__global__ __launch_bounds__(256, 4) void probe_kernel(
    const float* __restrict__ input,
    const int* __restrict__ lengths,
    float* __restrict__ ws) {
    const int b   = blockIdx.x >> 5;
    const int s   = blockIdx.x & 31;
    const int tid = threadIdx.x;
    const int c   = tid & 7;
    const int rp  = tid >> 3;
    const int len = lengths[b];

    const f32x4* __restrict__ in4 =
        (const f32x4*)input + (size_t)b * T * (D / 4) + s * (SLICE / 4) + c;

    float ax = 0.f, ay = 0.f, az = 0.f, aw = 0.f;
    const int nfull = len >> 5;
    const f32x4* p = in4 + (size_t)rp * (D / 4);
#pragma unroll 4
    for (int it = 0; it < nfull; ++it) {
        const f32x4 v = p[(size_t)it * 32 * (D / 4)];
        ax += v.x; ay += v.y; az += v.z; aw += v.w;
    }
    const int r = (nfull << 5) + rp;
    if (r < len) {
        const f32x4 v = in4[(size_t)r * (D / 4)];
        ax += v.x; ay += v.y; az += v.z; aw += v.w;
    }

    f32x4 o; o.x = ax; o.y = ay; o.z = az; o.w = aw;
    ((f32x4*)ws)[(size_t)blockIdx.x * 256 + tid] = o;
}

extern "C" void kernel_launch(void* const* d_in, const int* in_sizes, int n_in,
                              void* d_out, int out_size, void* d_ws, size_t ws_size,
                              hipStream_t stream) {
    const float* input   = (const float*)d_in[0];
    const int*   lengths = (const int*)d_in[1];
    const float* weights = (const float*)d_in[2];
    float* out = (float*)d_out;
    float* ws  = (float*)d_ws;

    fused1_kernel<<<B * NSLICE, 256, 0, stream>>>(input, lengths, weights, out);
    probe_kernel<<<B * NSLICE, 256, 0, stream>>>(input, lengths, ws);
}